// Round 12
// baseline (136.058 us; speedup 1.0000x reference)
//
#include <hip/hip_runtime.h>
#include <stdint.h>

typedef __attribute__((ext_vector_type(8))) short short8;
typedef __attribute__((ext_vector_type(4))) float floatx4;
typedef __attribute__((ext_vector_type(2))) float float2v;

#define MFMA(a, b, c) __builtin_amdgcn_mfma_f32_16x16x32_bf16(a, b, c, 0, 0, 0)

union Frag { uint32_t u[4]; short8 s; };
union PF2 { float2v f; uint32_t u[2]; };

// split fp32 x into hi=bf16(trunc), lo=bf16(trunc of exact residual); pack two
// values' bf16 halves into one dword (a -> low16, b -> high16).
__device__ __forceinline__ void packsplit(float a, float b, uint32_t& hi, uint32_t& lo) {
    uint32_t ua = __float_as_uint(a), ub = __float_as_uint(b);
    uint32_t ha = ua & 0xFFFF0000u, hb = ub & 0xFFFF0000u;
    float ra = a - __uint_as_float(ha);   // exact in fp32
    float rb = b - __uint_as_float(hb);
    hi = __builtin_amdgcn_perm(ub, ua, 0x07060302u);  // {ub.hi16 : ua.hi16}
    lo = __builtin_amdgcn_perm(__float_as_uint(rb), __float_as_uint(ra), 0x07060302u);
}

__device__ __forceinline__ float fexp2(float x) {
#if __has_builtin(__builtin_amdgcn_exp2f)
    return __builtin_amdgcn_exp2f(x);     // v_exp_f32 = 2^x
#else
    return exp2f(x);
#endif
}

// Raw barrier: LDS-visibility only. Global loads stay IN FLIGHT across it.
__device__ __forceinline__ void bar_lds() {
    asm volatile("s_waitcnt lgkmcnt(0)" ::: "memory");
    __builtin_amdgcn_s_barrier();
    __builtin_amdgcn_sched_barrier(0);
}

// ---------------- pre-pack kernel ----------------
// kpk dword layout: row = bh*512+m; [row*64 + 0..32) hi dwords (pair d/2),
//                   [row*64 + 32..64) lo dwords.  (pairs along d; no transpose)
// vpk dword layout: hi plane [(bh*64 + d)*256 + m2], lo plane at +VLO;
//                   dword(d,m2) = pack(V[2m2][d], V[2m2+1][d])  (m-pair transpose)
#define VLO 1048576
#define KPK_DW 2097152
#define WS_NEED ((size_t)(KPK_DW + 2 * VLO) * 4)

__global__ __launch_bounds__(256)
void packkv(const float* __restrict__ kg, const float* __restrict__ vg,
            uint32_t* __restrict__ kpk, uint32_t* __restrict__ vpk) {
    const int bid = blockIdx.x, tid = threadIdx.x;
    if (bid < 2048) {                      // K part: 32768 rows x 16 threads
        const int g   = bid * 256 + tid;
        const int row = g >> 4, q = g & 15;
        const float4 f = *(const float4*)(kg + (size_t)row * 64 + 4 * q);
        uint32_t h0, l0, h1, l1;
        packsplit(f.x, f.y, h0, l0);
        packsplit(f.z, f.w, h1, l1);
        uint32_t* rb = kpk + (size_t)row * 64;
        *(uint2*)(rb + 2 * q)      = make_uint2(h0, h1);
        *(uint2*)(rb + 32 + 2 * q) = make_uint2(l0, l1);
    } else {                               // V part: transpose to m-pairs
        const int vb  = bid - 2048;        // 0..1023
        const int bh  = vb >> 4, m2g = vb & 15;
        const int m2  = m2g * 16 + (tid & 15);   // 0..255
        const int dg  = tid >> 4;                // 0..15
        const float* r0 = vg + ((size_t)(bh * 512 + 2 * m2)) * 64 + 4 * dg;
        const float4 f0 = *(const float4*)(r0);
        const float4 f1 = *(const float4*)(r0 + 64);
        const float a0[4] = {f0.x, f0.y, f0.z, f0.w};
        const float a1[4] = {f1.x, f1.y, f1.z, f1.w};
#pragma unroll
        for (int jj = 0; jj < 4; ++jj) {
            uint32_t hh, ll;
            packsplit(a0[jj], a1[jj], hh, ll);
            const size_t o = (size_t)(bh * 64 + 4 * dg + jj) * 256 + m2;
            vpk[o]       = hh;
            vpk[VLO + o] = ll;
        }
    }
}

// ---------------- main kernel ----------------
// LDS map per group g (gb = g*8704): K hi/lo (64x32 dw, XOR swz, reused as P),
// V hi/lo (64 d-rows x 36 dw, rotated). Epilogue: O1 [64][65] @8704, l1 @12864.
// Unnormalized exp2 softmax (R10). PKD=1: K/V read pre-packed from workspace.

template <int PKD>
__global__ __attribute__((amdgpu_waves_per_eu(4))) __launch_bounds__(512)
void msmha_flash(const float* __restrict__ qg, const float* __restrict__ kg,
                 const float* __restrict__ vg, const float* __restrict__ Dg,
                 const float* __restrict__ m1w, const float* __restrict__ m1b,
                 const float* __restrict__ m2w, const float* __restrict__ m2b,
                 const uint32_t* __restrict__ kpk, const uint32_t* __restrict__ vpk,
                 float* __restrict__ outg) {
    __shared__ __align__(16) uint32_t sm[17408];   // 68 KiB
    __shared__ __align__(16) float4 wlds[16];

    const int tid   = threadIdx.x;
    const int w     = tid >> 6;
    const int group = w >> 2;
    const int gw    = w & 3;
    const int lane  = tid & 63;
    const int col   = lane & 15;
    const int quad  = lane >> 4;
    const int gtid  = tid & 255;

    // XCD-aware remap: all 8 T-tiles of one (b,h) land on ONE XCD's L2.
    const int bid = blockIdx.x;
    const int wgT = bid >> 6;
    const int bh  = bid & 63;
    const int h   = bh & 15;
    const int b   = bh >> 4;
    const int t0g = wgT * 64;

    const size_t base = (size_t)bh * 512 * 64;
    const float LOG2E = 1.4426950408889634f;

    if (tid < 16) {
        const float w1d = m1w[h * 32 + tid];
        const float w1s = m1w[h * 32 + 16 + tid];
        const float b1  = m1b[h * 16 + tid];
        const float w2  = m2w[h * 16 + tid];
        wlds[tid] = make_float4(w1d * (0.125f * LOG2E), w1s * LOG2E, b1 * LOG2E, 0.5f * w2);
    }

    const int krow = 16 * gw + (lane >> 2);
    const int kqt  = lane & 3;
    const int ksw  = (krow & 7) << 2;
    const int rsw  = (col & 7) << 2;
    const int dgrp = gtid & 15;
    const int m4   = gtid >> 4;
    const int cpV  = (2 * m4 + 8 * ((dgrp >> 1) & 3)) & 31;
    const int rsel = col >> 3;

    const int gb = group * 8704;
    uint32_t* KH = sm + gb;
    uint32_t* KL = sm + gb + 2048;
    uint32_t* VH = sm + gb + 4096;
    uint32_t* VL = sm + gb + 6400;

    const int moff = group * 256;
    const float* kc = kg + base + (size_t)moff * 64;
    const float* vc = vg + base + (size_t)moff * 64;
    const float* Dc = Dg + ((size_t)b * 512 + t0g + gw * 16 + col) * 512 + moff + quad * 4;

    // Linear half of relu split: sum_c w2*relu(h) = sum_c (w2/2)h + (w2/2)|h|
    float sA = 0.f, sB = 0.f, sC = 0.f;
#pragma unroll 1
    for (int c = 0; c < 16; ++c) {
        const float w2 = m2w[h * 16 + c];
        sA = fmaf(w2, m1w[h * 32 + c], sA);
        sB = fmaf(w2, m1w[h * 32 + 16 + c], sB);
        sC = fmaf(w2, m1b[h * 16 + c], sC);
    }
    const float Ac = sA * (0.0625f * LOG2E);
    const float Bc = sB * (0.5f * LOG2E);
    const float Cc = fmaf(0.5f, sC, m2b[h]) * LOG2E;

    // Q fragments (B-operand), split bf16
    Frag qh[2], ql[2];
    {
        const float* qrow = qg + base + (size_t)(t0g + gw * 16 + col) * 64;
#pragma unroll
        for (int ks = 0; ks < 2; ++ks) {
            const float4 f0 = *(const float4*)(qrow + ks * 32 + quad * 8);
            const float4 f1 = *(const float4*)(qrow + ks * 32 + quad * 8 + 4);
            packsplit(f0.x, f0.y, qh[ks].u[0], ql[ks].u[0]);
            packsplit(f0.z, f0.w, qh[ks].u[1], ql[ks].u[1]);
            packsplit(f1.x, f1.y, qh[ks].u[2], ql[ks].u[2]);
            packsplit(f1.z, f1.w, qh[ks].u[3], ql[ks].u[3]);
        }
    }

    float lsum = 0.f;
    floatx4 oacc[4];
#pragma unroll
    for (int dt = 0; dt < 4; ++dt) oacc[dt] = floatx4{0.f, 0.f, 0.f, 0.f};

    const float2v Ac2 = {Ac, Ac}, Bc2 = {Bc, Bc}, Cc2 = {Cc, Cc};

#pragma unroll 1
    for (int mc = 0; mc < 4; ++mc) {
        float4 dp[4];
        floatx4 sc[4];

        if constexpr (PKD) {
            // ---- pre-packed staging: pure loads + ds_write, zero pack VALU ----
            uint2 khl[4], kll[4], vhl[4], vll[4];
            const size_t krb = ((size_t)(bh * 512 + moff + mc * 64 + krow)) * 64;
#pragma unroll
            for (int i = 0; i < 4; ++i) {
                khl[i] = *(const uint2*)(kpk + krb + 8 * i + 2 * kqt);
                kll[i] = *(const uint2*)(kpk + krb + 32 + 8 * i + 2 * kqt);
            }
#pragma unroll
            for (int jj = 0; jj < 4; ++jj) {
                const size_t vbd = (size_t)(bh * 64 + 4 * dgrp + jj) * 256
                                 + 128 * group + 32 * mc + 2 * m4;
                vhl[jj] = *(const uint2*)(vpk + vbd);
                vll[jj] = *(const uint2*)(vpk + VLO + vbd);
            }
#pragma unroll
            for (int mt = 0; mt < 4; ++mt)
                dp[mt] = *(const float4*)(Dc + mc * 64 + mt * 16);

#pragma unroll
            for (int i = 0; i < 4; ++i) {
                const int off = (8 * i + 2 * kqt) ^ ksw;
                *(uint2*)(KH + krow * 32 + off) = khl[i];
                *(uint2*)(KL + krow * 32 + off) = kll[i];
            }
            bar_lds();                         // --- bar1: K staged ---

            __builtin_amdgcn_s_setprio(1);
#pragma unroll
            for (int mt = 0; mt < 4; ++mt) {
                floatx4 acc = {0.f, 0.f, 0.f, 0.f};
#pragma unroll
                for (int ks = 0; ks < 2; ++ks) {
                    const int ro = (mt * 16 + col) * 32 + ((16 * ks + 4 * quad) ^ rsw);
                    Frag ah, al;
                    ah.s = *(const short8*)(KH + ro);
                    al.s = *(const short8*)(KL + ro);
                    acc = MFMA(ah.s, qh[ks].s, acc);
                    acc = MFMA(ah.s, ql[ks].s, acc);
                    acc = MFMA(al.s, qh[ks].s, acc);
                }
                sc[mt] = acc;
            }
            __builtin_amdgcn_s_setprio(0);

#pragma unroll
            for (int jj = 0; jj < 4; ++jj) {
                const int d = 4 * dgrp + jj;
                *(uint2*)(VH + d * 36 + cpV) = vhl[jj];
                *(uint2*)(VL + d * 36 + cpV) = vll[jj];
            }
        } else {
            // ---- fallback staging (R11): float loads + in-kernel packsplit ----
            float4 kp[4], vp[4];
#pragma unroll
            for (int i = 0; i < 4; ++i)
                kp[i] = *(const float4*)(kc + (size_t)(mc * 64 + krow) * 64 + 16 * i + 4 * kqt);
#pragma unroll
            for (int i = 0; i < 4; ++i)
                vp[i] = *(const float4*)(vc + (size_t)(mc * 64 + 4 * m4 + i) * 64 + dgrp * 4);
#pragma unroll
            for (int mt = 0; mt < 4; ++mt)
                dp[mt] = *(const float4*)(Dc + mc * 64 + mt * 16);

#pragma unroll
            for (int i = 0; i < 4; ++i) {
                uint32_t h0, l0, h1, l1;
                packsplit(kp[i].x, kp[i].y, h0, l0);
                packsplit(kp[i].z, kp[i].w, h1, l1);
                const int off = (8 * i + 2 * kqt) ^ ksw;
                *(uint2*)(KH + krow * 32 + off) = make_uint2(h0, h1);
                *(uint2*)(KL + krow * 32 + off) = make_uint2(l0, l1);
            }
            bar_lds();                         // --- bar1: K staged ---

            __builtin_amdgcn_s_setprio(1);
#pragma unroll
            for (int mt = 0; mt < 4; ++mt) {
                floatx4 acc = {0.f, 0.f, 0.f, 0.f};
#pragma unroll
                for (int ks = 0; ks < 2; ++ks) {
                    const int ro = (mt * 16 + col) * 32 + ((16 * ks + 4 * quad) ^ rsw);
                    Frag ah, al;
                    ah.s = *(const short8*)(KH + ro);
                    al.s = *(const short8*)(KL + ro);
                    acc = MFMA(ah.s, qh[ks].s, acc);
                    acc = MFMA(ah.s, ql[ks].s, acc);
                    acc = MFMA(al.s, qh[ks].s, acc);
                }
                sc[mt] = acc;
            }
            __builtin_amdgcn_s_setprio(0);

#pragma unroll
            for (int jj = 0; jj < 4; ++jj) {
                uint32_t h0, l0, h1, l1;
                packsplit(((const float*)&vp[0])[jj], ((const float*)&vp[1])[jj], h0, l0);
                packsplit(((const float*)&vp[2])[jj], ((const float*)&vp[3])[jj], h1, l1);
                const int d = 4 * dgrp + jj;
                *(uint2*)(VH + d * 36 + cpV) = make_uint2(h0, h1);
                *(uint2*)(VL + d * 36 + cpV) = make_uint2(l0, l1);
            }
        }

        // fused MLP, packed f32 (v_pk_fma_f32), two halves of 8 elements.
        // mix = Cc + Bc*D + Ac*dot + sum_c (w2/2)|h_c|; abs via bit-AND per half.
#pragma unroll
        for (int half = 0; half < 2; ++half) {
            float2v s2v[4], dv2[4], mx2[4];
#pragma unroll
            for (int p = 0; p < 4; ++p) {
                const int mt = 2 * half + (p >> 1), eo = 2 * (p & 1);
                s2v[p] = float2v{sc[mt][eo], sc[mt][eo + 1]};
                const float4 dd = dp[mt];
                dv2[p] = (p & 1) ? float2v{dd.z, dd.w} : float2v{dd.x, dd.y};
            }
#pragma unroll
            for (int p = 0; p < 4; ++p) mx2[p] = dv2[p] * Bc2 + Cc2;
#pragma unroll 4
            for (int c = 0; c < 16; ++c) {
                const float4 wv = wlds[c];
                const float2v wx2 = {wv.x, wv.x}, wy2 = {wv.y, wv.y};
                const float2v wz2 = {wv.z, wv.z}, ww2 = {wv.w, wv.w};
#pragma unroll
                for (int p = 0; p < 4; ++p) {
                    PF2 a;
                    a.f = s2v[p] * wx2 + (dv2[p] * wy2 + wz2);
                    a.u[0] &= 0x7fffffffu;
                    a.u[1] &= 0x7fffffffu;
                    mx2[p] = a.f * ww2 + mx2[p];
                }
            }
#pragma unroll
            for (int p = 0; p < 4; ++p) {
                const float2v sco = s2v[p] * Ac2 + mx2[p];   // log2-domain score
                const float px = fexp2(sco.x), py = fexp2(sco.y);
                const int mt = 2 * half + (p >> 1), eo = 2 * (p & 1);
                sc[mt][eo]     = px;
                sc[mt][eo + 1] = py;
                lsum += px;
                lsum += py;
            }
        }

        bar_lds();                             // --- bar2: QK reads done; V visible ---

        // P -> LDS (own rows in K region; swizzled like K)
        const int prow = (gw * 16 + col) * 32;
#pragma unroll
        for (int mt = 0; mt < 4; ++mt) {
            uint32_t h0, l0, h1, l1;
            packsplit(sc[mt][0], sc[mt][1], h0, l0);
            packsplit(sc[mt][2], sc[mt][3], h1, l1);
            const int off = (mt * 8 + 2 * quad) ^ rsw;
            *(uint2*)(KH + prow + off) = make_uint2(h0, h1);
            *(uint2*)(KL + prow + off) = make_uint2(l0, l1);
        }

        // O += P·V   (no trailing barrier: next K-pack touches only OWN rows)
        __builtin_amdgcn_s_setprio(1);
#pragma unroll
        for (int ks = 0; ks < 2; ++ks) {
            const int po = prow + ((16 * ks + 4 * quad) ^ rsw);
            Frag pah, pal;
            pah.s = *(const short8*)(KH + po);
            pal.s = *(const short8*)(KL + po);
#pragma unroll
            for (int dt = 0; dt < 4; ++dt) {
                const int cbd = ((16 * ks + 4 * quad) + 8 * ((2 * dt + rsel) & 3)) & 31;
                const int vo = (dt * 16 + col) * 36 + cbd;
                Frag bhv, blv;
                bhv.s = *(const short8*)(VH + vo);
                blv.s = *(const short8*)(VL + vo);
                oacc[dt] = MFMA(pah.s, bhv.s, oacc[dt]);
                oacc[dt] = MFMA(pah.s, blv.s, oacc[dt]);
                oacc[dt] = MFMA(pal.s, bhv.s, oacc[dt]);
            }
        }
        __builtin_amdgcn_s_setprio(0);
    }

    bar_lds();                                 // all PV reads done before epilogue writes

    lsum += __shfl_xor(lsum, 16, 64);
    lsum += __shfl_xor(lsum, 32, 64);

    float* smf = (float*)sm;
    if (group == 1) {
        if (quad == 0) smf[12864 + gw * 16 + col] = lsum;
        const int t = gw * 16 + quad * 4;
#pragma unroll
        for (int dt = 0; dt < 4; ++dt)
#pragma unroll
            for (int r = 0; r < 4; ++r)
                smf[8704 + (t + r) * 65 + dt * 16 + col] = oacc[dt][r];
    }
    bar_lds();
    if (group == 0) {
        const float l1c = smf[12864 + gw * 16 + col];
        const float rdn = 1.f / (lsum + l1c);
        float rdT[4];
#pragma unroll
        for (int r = 0; r < 4; ++r)
            rdT[r] = __shfl(rdn, quad * 4 + r, 64);
        const int t = gw * 16 + quad * 4;
        const size_t obase = ((size_t)b * 512 + t0g + t) * 1024 + h * 64 + col;
#pragma unroll
        for (int dt = 0; dt < 4; ++dt)
#pragma unroll
            for (int r = 0; r < 4; ++r) {
                const float o1 = smf[8704 + (t + r) * 65 + dt * 16 + col];
                outg[obase + (size_t)r * 1024 + dt * 16] = (oacc[dt][r] + o1) * rdT[r];
            }
    }
}

extern "C" void kernel_launch(void* const* d_in, const int* in_sizes, int n_in,
                              void* d_out, int out_size, void* d_ws, size_t ws_size,
                              hipStream_t stream) {
    const float* q   = (const float*)d_in[0];
    const float* k   = (const float*)d_in[1];
    const float* v   = (const float*)d_in[2];
    const float* dtm = (const float*)d_in[3];
    const float* m1w = (const float*)d_in[4];
    const float* m1b = (const float*)d_in[5];
    const float* m2w = (const float*)d_in[6];
    const float* m2b = (const float*)d_in[7];
    float* out = (float*)d_out;

    dim3 grid(4 * 16 * 8);   // 512 workgroups: (b,h) x 8 T-tiles
    dim3 block(512);         // 8 waves: 2 m-groups x 4 t-tiles

    if (d_ws != nullptr && ws_size >= WS_NEED) {
        uint32_t* kpk = (uint32_t*)d_ws;
        uint32_t* vpk = kpk + KPK_DW;
        packkv<<<dim3(3072), dim3(256), 0, stream>>>(k, v, kpk, vpk);
        msmha_flash<1><<<grid, block, 0, stream>>>(q, k, v, dtm, m1w, m1b, m2w, m2b,
                                                   kpk, vpk, out);
    } else {
        msmha_flash<0><<<grid, block, 0, stream>>>(q, k, v, dtm, m1w, m1b, m2w, m2b,
                                                   nullptr, nullptr, out);
    }
}

// Round 13
// 135.286 us; speedup vs baseline: 1.0057x; 1.0057x over previous
//
#include <hip/hip_runtime.h>
#include <stdint.h>

typedef __attribute__((ext_vector_type(8))) short short8;
typedef __attribute__((ext_vector_type(4))) float floatx4;

#define MFMA(a, b, c) __builtin_amdgcn_mfma_f32_16x16x32_bf16(a, b, c, 0, 0, 0)

union Frag { uint32_t u[4]; short8 s; };

// split fp32 x into hi=bf16(trunc), lo=bf16(trunc of exact residual); pack two
// values' bf16 halves into one dword (a -> low16, b -> high16).
__device__ __forceinline__ void packsplit(float a, float b, uint32_t& hi, uint32_t& lo) {
    uint32_t ua = __float_as_uint(a), ub = __float_as_uint(b);
    uint32_t ha = ua & 0xFFFF0000u, hb = ub & 0xFFFF0000u;
    float ra = a - __uint_as_float(ha);   // exact in fp32
    float rb = b - __uint_as_float(hb);
    hi = __builtin_amdgcn_perm(ub, ua, 0x07060302u);  // {ub.hi16 : ua.hi16}
    lo = __builtin_amdgcn_perm(__float_as_uint(rb), __float_as_uint(ra), 0x07060302u);
}

__device__ __forceinline__ float fexp2(float x) {
#if __has_builtin(__builtin_amdgcn_exp2f)
    return __builtin_amdgcn_exp2f(x);     // v_exp_f32 = 2^x
#else
    return exp2f(x);
#endif
}

// Raw barrier: LDS-visibility only. Global loads stay IN FLIGHT across it.
__device__ __forceinline__ void bar_lds() {
    asm volatile("s_waitcnt lgkmcnt(0)" ::: "memory");
    __builtin_amdgcn_s_barrier();
    __builtin_amdgcn_sched_barrier(0);
}

// LDS dword map, per group g (gb = g*8704):
//   K hi gb+0..2048      64 rows x 32 dw, XOR-swizzled (off ^ (row&7)<<2)
//   K lo gb+2048..4096   (K region reused as P after QK; same swizzle)
//   V hi gb+4096..6400   64 d-rows x 36 dw, rotated cols
//   V lo gb+6400..8704
// Epilogue (group-1 region): O1 fp32 [64][65] @8704, l1 @12864.
//
// Unnormalized exp2 softmax (R10: scores bounded, no max/rescale needed).
// R13 = R11 + K one-chunk-ahead prefetch (the only load with zero latency
// cover in R11); fits the 128-reg combined budget after R11's slimming.

__attribute__((amdgpu_waves_per_eu(4)))
__global__ __launch_bounds__(512)
void msmha_flash(const float* __restrict__ qg, const float* __restrict__ kg,
                 const float* __restrict__ vg, const float* __restrict__ Dg,
                 const float* __restrict__ m1w, const float* __restrict__ m1b,
                 const float* __restrict__ m2w, const float* __restrict__ m2b,
                 float* __restrict__ outg) {
    __shared__ __align__(16) uint32_t sm[17408];   // 68 KiB
    __shared__ __align__(16) float4 wlds[16];

    const int tid   = threadIdx.x;
    const int w     = tid >> 6;
    const int group = w >> 2;          // 0: m in [0,256), 1: m in [256,512)
    const int gw    = w & 3;           // t-tile within group (16 t-rows)
    const int lane  = tid & 63;
    const int col   = lane & 15;
    const int quad  = lane >> 4;
    const int gtid  = tid & 255;

    // XCD-aware remap: all 8 T-tiles of one (b,h) land on ONE XCD's L2.
    const int bid = blockIdx.x;
    const int wgT = bid >> 6;
    const int bh  = bid & 63;
    const int h   = bh & 15;
    const int b   = bh >> 4;
    const int t0g = wgT * 64;

    const size_t base = (size_t)bh * 512 * 64;
    const float LOG2E = 1.4426950408889634f;

    if (tid < 16) {
        const float w1d = m1w[h * 32 + tid];
        const float w1s = m1w[h * 32 + 16 + tid];
        const float b1  = m1b[h * 16 + tid];
        const float w2  = m2w[h * 16 + tid];
        wlds[tid] = make_float4(w1d * (0.125f * LOG2E), w1s * LOG2E, b1 * LOG2E, 0.5f * w2);
    }

    // staging indices
    const int krow = 16 * gw + (lane >> 2);     // K/P row ownership: wave's own 16 rows
    const int kqt  = lane & 3;                  // quarter-row (16 floats each)
    const int ksw  = (krow & 7) << 2;           // K write swizzle
    const int rsw  = (col & 7) << 2;            // K/P read swizzle
    const int dgrp = gtid & 15;                 // V d-group (4 d per thread)
    const int m4   = gtid >> 4;                 // V m-group (4 m per thread)
    const int cpV  = (2 * m4 + 8 * ((dgrp >> 1) & 3)) & 31;   // V write rotation
    const int rsel = col >> 3;

    const int gb = group * 8704;
    uint32_t* KH = sm + gb;
    uint32_t* KL = sm + gb + 2048;
    uint32_t* VH = sm + gb + 4096;
    uint32_t* VL = sm + gb + 6400;

    const int moff = group * 256;
    const float* kc = kg + base + (size_t)moff * 64;
    const float* vc = vg + base + (size_t)moff * 64;
    const float* Dc = Dg + ((size_t)b * 512 + t0g + gw * 16 + col) * 512 + moff + quad * 4;

    // ---------- prologue: chunk-0 K load issued FIRST (long cover below) ----------
    float4 kp[4];
#pragma unroll
    for (int i = 0; i < 4; ++i)
        kp[i] = *(const float4*)(kc + (size_t)krow * 64 + 16 * i + 4 * kqt);

    // Linear half of relu split: sum_c w2*relu(h) = sum_c (w2/2)h + (w2/2)|h|
    float sA = 0.f, sB = 0.f, sC = 0.f;
#pragma unroll 1
    for (int c = 0; c < 16; ++c) {
        const float w2 = m2w[h * 16 + c];
        sA = fmaf(w2, m1w[h * 32 + c], sA);
        sB = fmaf(w2, m1w[h * 32 + 16 + c], sB);
        sC = fmaf(w2, m1b[h * 16 + c], sC);
    }
    const float Ac = sA * (0.0625f * LOG2E);
    const float Bc = sB * (0.5f * LOG2E);
    const float Cc = fmaf(0.5f, sC, m2b[h]) * LOG2E;

    // Q fragments (B-operand), split bf16
    Frag qh[2], ql[2];
    {
        const float* qrow = qg + base + (size_t)(t0g + gw * 16 + col) * 64;
#pragma unroll
        for (int ks = 0; ks < 2; ++ks) {
            const float4 f0 = *(const float4*)(qrow + ks * 32 + quad * 8);
            const float4 f1 = *(const float4*)(qrow + ks * 32 + quad * 8 + 4);
            packsplit(f0.x, f0.y, qh[ks].u[0], ql[ks].u[0]);
            packsplit(f0.z, f0.w, qh[ks].u[1], ql[ks].u[1]);
            packsplit(f1.x, f1.y, qh[ks].u[2], ql[ks].u[2]);
            packsplit(f1.z, f1.w, qh[ks].u[3], ql[ks].u[3]);
        }
    }

    float lsum = 0.f;                  // lane-local unnormalized softmax sum
    floatx4 oacc[4];
#pragma unroll
    for (int dt = 0; dt < 4; ++dt) oacc[dt] = floatx4{0.f, 0.f, 0.f, 0.f};

#pragma unroll 1
    for (int mc = 0; mc < 4; ++mc) {
        // JIT V/D loads (L2-resident after XCD remap; QK-phase covers them)
        float4 vp[4], dp[4];
#pragma unroll
        for (int i = 0; i < 4; ++i)
            vp[i] = *(const float4*)(vc + (size_t)(mc * 64 + 4 * m4 + i) * 64 + dgrp * 4);
#pragma unroll
        for (int mt = 0; mt < 4; ++mt)
            dp[mt] = *(const float4*)(Dc + mc * 64 + mt * 16);

        // pack K[mc] -> LDS (own 16 rows; XOR swizzle). kp was issued a full
        // chunk ago (prologue / previous iteration) -> latency fully covered;
        // the vmcnt wait here leaves this iter's V/D loads in flight.
#pragma unroll
        for (int i = 0; i < 4; ++i) {
            uint32_t h0, l0, h1, l1;
            packsplit(kp[i].x, kp[i].y, h0, l0);
            packsplit(kp[i].z, kp[i].w, h1, l1);
            const int off = (8 * i + 2 * kqt) ^ ksw;
            *(uint2*)(KH + krow * 32 + off) = make_uint2(h0, h1);
            *(uint2*)(KL + krow * 32 + off) = make_uint2(l0, l1);
        }
        // prefetch K[mc+1] into the just-consumed buffer; stays in flight
        // across bar1/QK/MLP/bar2/PV (~2000+ cy of cover).
        if (mc < 3) {
#pragma unroll
            for (int i = 0; i < 4; ++i)
                kp[i] = *(const float4*)(kc + (size_t)((mc + 1) * 64 + krow) * 64 + 16 * i + 4 * kqt);
        }
        bar_lds();                             // --- bar1: K staged ---

        // S^T = K·Q^T via split bf16
        floatx4 sc[4];
        __builtin_amdgcn_s_setprio(1);
#pragma unroll
        for (int mt = 0; mt < 4; ++mt) {
            floatx4 acc = {0.f, 0.f, 0.f, 0.f};
#pragma unroll
            for (int ks = 0; ks < 2; ++ks) {
                const int ro = (mt * 16 + col) * 32 + ((16 * ks + 4 * quad) ^ rsw);
                Frag ah, al;
                ah.s = *(const short8*)(KH + ro);
                al.s = *(const short8*)(KL + ro);
                acc = MFMA(ah.s, qh[ks].s, acc);
                acc = MFMA(ah.s, ql[ks].s, acc);
                acc = MFMA(al.s, qh[ks].s, acc);
            }
            sc[mt] = acc;
        }
        __builtin_amdgcn_s_setprio(0);

        // pack V[mc] -> LDS (published by bar2); frees vp before MLP peak
#pragma unroll
        for (int jj = 0; jj < 4; ++jj) {
            uint32_t h0, l0, h1, l1;
            packsplit(((const float*)&vp[0])[jj], ((const float*)&vp[1])[jj], h0, l0);
            packsplit(((const float*)&vp[2])[jj], ((const float*)&vp[3])[jj], h1, l1);
            const int d = 4 * dgrp + jj;
            *(uint2*)(VH + d * 36 + cpV) = make_uint2(h0, h1);
            *(uint2*)(VL + d * 36 + cpV) = make_uint2(l0, l1);
        }

        // fused MLP in TWO HALVES of 8 elements (register-peak control).
        // mix = Cc + Bc*D + Ac*dot + sum_c (w2/2)|h_c|; |..| is free modifier.
        // P = 2^score written in-place into sc.
#pragma unroll
        for (int half = 0; half < 2; ++half) {
            float dvf[8], mix[8];
#pragma unroll
            for (int q2 = 0; q2 < 2; ++q2) {
                const float4 dd = dp[2 * half + q2];
                dvf[q2 * 4 + 0] = dd.x; dvf[q2 * 4 + 1] = dd.y;
                dvf[q2 * 4 + 2] = dd.z; dvf[q2 * 4 + 3] = dd.w;
            }
#pragma unroll
            for (int e = 0; e < 8; ++e) mix[e] = fmaf(dvf[e], Bc, Cc);
#pragma unroll 4
            for (int c = 0; c < 16; ++c) {
                const float4 wv = wlds[c];
#pragma unroll
                for (int e = 0; e < 8; ++e) {
                    const float s = sc[2 * half + (e >> 2)][e & 3];
                    const float hh = fmaf(s, wv.x, fmaf(dvf[e], wv.y, wv.z));
                    mix[e] = fmaf(fabsf(hh), wv.w, mix[e]);
                }
            }
#pragma unroll
            for (int e = 0; e < 8; ++e) {
                const float s = sc[2 * half + (e >> 2)][e & 3];
                const float p = fexp2(fmaf(s, Ac, mix[e]));
                sc[2 * half + (e >> 2)][e & 3] = p;    // P in place
                lsum += p;
            }
        }

        bar_lds();                             // --- bar2: QK reads done; V visible ---

        // P -> LDS (own rows in K region; swizzled like K)
        const int prow = (gw * 16 + col) * 32;
#pragma unroll
        for (int mt = 0; mt < 4; ++mt) {
            uint32_t h0, l0, h1, l1;
            packsplit(sc[mt][0], sc[mt][1], h0, l0);
            packsplit(sc[mt][2], sc[mt][3], h1, l1);
            const int off = (mt * 8 + 2 * quad) ^ rsw;
            *(uint2*)(KH + prow + off) = make_uint2(h0, h1);
            *(uint2*)(KL + prow + off) = make_uint2(l0, l1);
        }

        // O += P·V   (no trailing barrier: next K-pack touches only OWN rows)
        __builtin_amdgcn_s_setprio(1);
#pragma unroll
        for (int ks = 0; ks < 2; ++ks) {
            const int po = prow + ((16 * ks + 4 * quad) ^ rsw);
            Frag pah, pal;
            pah.s = *(const short8*)(KH + po);
            pal.s = *(const short8*)(KL + po);
#pragma unroll
            for (int dt = 0; dt < 4; ++dt) {
                const int cbd = ((16 * ks + 4 * quad) + 8 * ((2 * dt + rsel) & 3)) & 31;
                const int vo = (dt * 16 + col) * 36 + cbd;
                Frag bhv, blv;
                bhv.s = *(const short8*)(VH + vo);
                blv.s = *(const short8*)(VL + vo);
                oacc[dt] = MFMA(pah.s, bhv.s, oacc[dt]);
                oacc[dt] = MFMA(pah.s, blv.s, oacc[dt]);
                oacc[dt] = MFMA(pal.s, bhv.s, oacc[dt]);
            }
        }
        __builtin_amdgcn_s_setprio(0);
    }

    bar_lds();                                 // all PV reads done before epilogue writes

    // single end-of-loop l reduction (t = col)
    lsum += __shfl_xor(lsum, 16, 64);
    lsum += __shfl_xor(lsum, 32, 64);

    // ================= combine the two m-halves, store =================
    float* smf = (float*)sm;
    if (group == 1) {
        if (quad == 0) smf[12864 + gw * 16 + col] = lsum;
        const int t = gw * 16 + quad * 4;
#pragma unroll
        for (int dt = 0; dt < 4; ++dt)
#pragma unroll
            for (int r = 0; r < 4; ++r)
                smf[8704 + (t + r) * 65 + dt * 16 + col] = oacc[dt][r];
    }
    bar_lds();
    if (group == 0) {
        const float l1c = smf[12864 + gw * 16 + col];
        const float rdn = 1.f / (lsum + l1c);
        float rdT[4];
#pragma unroll
        for (int r = 0; r < 4; ++r)
            rdT[r] = __shfl(rdn, quad * 4 + r, 64);
        const int t = gw * 16 + quad * 4;
        const size_t obase = ((size_t)b * 512 + t0g + t) * 1024 + h * 64 + col;
#pragma unroll
        for (int dt = 0; dt < 4; ++dt)
#pragma unroll
            for (int r = 0; r < 4; ++r) {
                const float o1 = smf[8704 + (t + r) * 65 + dt * 16 + col];
                outg[obase + (size_t)r * 1024 + dt * 16] = (oacc[dt][r] + o1) * rdT[r];
            }
    }
}

extern "C" void kernel_launch(void* const* d_in, const int* in_sizes, int n_in,
                              void* d_out, int out_size, void* d_ws, size_t ws_size,
                              hipStream_t stream) {
    const float* q   = (const float*)d_in[0];
    const float* k   = (const float*)d_in[1];
    const float* v   = (const float*)d_in[2];
    const float* dtm = (const float*)d_in[3];
    const float* m1w = (const float*)d_in[4];
    const float* m1b = (const float*)d_in[5];
    const float* m2w = (const float*)d_in[6];
    const float* m2b = (const float*)d_in[7];
    float* out = (float*)d_out;

    dim3 grid(4 * 16 * 8);   // 512 workgroups: (b,h) x 8 T-tiles
    dim3 block(512);         // 8 waves: 2 m-groups x 4 t-tiles
    msmha_flash<<<grid, block, 0, stream>>>(q, k, v, dtm, m1w, m1b, m2w, m2b, out);
}

// Round 14
// 133.093 us; speedup vs baseline: 1.0223x; 1.0165x over previous
//
#include <hip/hip_runtime.h>
#include <stdint.h>

typedef __attribute__((ext_vector_type(8))) short short8;
typedef __attribute__((ext_vector_type(4))) float floatx4;

#define MFMA(a, b, c) __builtin_amdgcn_mfma_f32_16x16x32_bf16(a, b, c, 0, 0, 0)

union Frag { uint32_t u[4]; short8 s; };

// split fp32 x into hi=bf16(trunc), lo=bf16(trunc of exact residual); pack two
// values' bf16 halves into one dword (a -> low16, b -> high16).
__device__ __forceinline__ void packsplit(float a, float b, uint32_t& hi, uint32_t& lo) {
    uint32_t ua = __float_as_uint(a), ub = __float_as_uint(b);
    uint32_t ha = ua & 0xFFFF0000u, hb = ub & 0xFFFF0000u;
    float ra = a - __uint_as_float(ha);   // exact in fp32
    float rb = b - __uint_as_float(hb);
    hi = __builtin_amdgcn_perm(ub, ua, 0x07060302u);  // {ub.hi16 : ua.hi16}
    lo = __builtin_amdgcn_perm(__float_as_uint(rb), __float_as_uint(ra), 0x07060302u);
}

__device__ __forceinline__ float fexp2(float x) {
#if __has_builtin(__builtin_amdgcn_exp2f)
    return __builtin_amdgcn_exp2f(x);     // v_exp_f32 = 2^x
#else
    return exp2f(x);
#endif
}

// Raw barrier: LDS-visibility only. Global loads stay IN FLIGHT across it.
__device__ __forceinline__ void bar_lds() {
    asm volatile("s_waitcnt lgkmcnt(0)" ::: "memory");
    __builtin_amdgcn_s_barrier();
    __builtin_amdgcn_sched_barrier(0);
}

// LDS dword map, per group g (gb = g*8704):
//   K hi gb+0..2048      64 rows x 32 dw, XOR-swizzled (off ^ (row&7)<<2)
//   K lo gb+2048..4096   (K region reused as P after QK; same swizzle)
//   V hi gb+4096..6400   64 d-rows x 36 dw, rotated cols
//   V lo gb+6400..8704
// Epilogue (group-1 region): O1 fp32 [64][65] @8704, l1 @12864.
//
// Unnormalized exp2 softmax (R10: scores bounded, no max/rescale needed).
// R14 = R11 + K prefetch issued AFTER the P-pack: sc dies at P-pack, kp is
// born there -> disjoint live ranges, MLP register peak unchanged (the
// combined VGPR+AGPR budget at 4 waves/SIMD is exactly saturated by R11;
// R13 proved any overlap with the MLP peak spills).

__attribute__((amdgpu_waves_per_eu(4)))
__global__ __launch_bounds__(512)
void msmha_flash(const float* __restrict__ qg, const float* __restrict__ kg,
                 const float* __restrict__ vg, const float* __restrict__ Dg,
                 const float* __restrict__ m1w, const float* __restrict__ m1b,
                 const float* __restrict__ m2w, const float* __restrict__ m2b,
                 float* __restrict__ outg) {
    __shared__ __align__(16) uint32_t sm[17408];   // 68 KiB
    __shared__ __align__(16) float4 wlds[16];

    const int tid   = threadIdx.x;
    const int w     = tid >> 6;
    const int group = w >> 2;          // 0: m in [0,256), 1: m in [256,512)
    const int gw    = w & 3;           // t-tile within group (16 t-rows)
    const int lane  = tid & 63;
    const int col   = lane & 15;
    const int quad  = lane >> 4;
    const int gtid  = tid & 255;

    // XCD-aware remap: all 8 T-tiles of one (b,h) land on ONE XCD's L2.
    const int bid = blockIdx.x;
    const int wgT = bid >> 6;
    const int bh  = bid & 63;
    const int h   = bh & 15;
    const int b   = bh >> 4;
    const int t0g = wgT * 64;

    const size_t base = (size_t)bh * 512 * 64;
    const float LOG2E = 1.4426950408889634f;

    if (tid < 16) {
        const float w1d = m1w[h * 32 + tid];
        const float w1s = m1w[h * 32 + 16 + tid];
        const float b1  = m1b[h * 16 + tid];
        const float w2  = m2w[h * 16 + tid];
        wlds[tid] = make_float4(w1d * (0.125f * LOG2E), w1s * LOG2E, b1 * LOG2E, 0.5f * w2);
    }

    // staging indices
    const int krow = 16 * gw + (lane >> 2);     // K/P row ownership: wave's own 16 rows
    const int kqt  = lane & 3;                  // quarter-row (16 floats each)
    const int ksw  = (krow & 7) << 2;           // K write swizzle
    const int rsw  = (col & 7) << 2;            // K/P read swizzle
    const int dgrp = gtid & 15;                 // V d-group (4 d per thread)
    const int m4   = gtid >> 4;                 // V m-group (4 m per thread)
    const int cpV  = (2 * m4 + 8 * ((dgrp >> 1) & 3)) & 31;   // V write rotation
    const int rsel = col >> 3;

    const int gb = group * 8704;
    uint32_t* KH = sm + gb;
    uint32_t* KL = sm + gb + 2048;
    uint32_t* VH = sm + gb + 4096;
    uint32_t* VL = sm + gb + 6400;

    const int moff = group * 256;
    const float* kc = kg + base + (size_t)moff * 64;
    const float* vc = vg + base + (size_t)moff * 64;
    const float* Dc = Dg + ((size_t)b * 512 + t0g + gw * 16 + col) * 512 + moff + quad * 4;

    // ---------- prologue: chunk-0 K load issued FIRST ----------
    float4 kp[4];
#pragma unroll
    for (int i = 0; i < 4; ++i)
        kp[i] = *(const float4*)(kc + (size_t)krow * 64 + 16 * i + 4 * kqt);

    // Linear half of relu split: sum_c w2*relu(h) = sum_c (w2/2)h + (w2/2)|h|
    float sA = 0.f, sB = 0.f, sC = 0.f;
#pragma unroll 1
    for (int c = 0; c < 16; ++c) {
        const float w2 = m2w[h * 16 + c];
        sA = fmaf(w2, m1w[h * 32 + c], sA);
        sB = fmaf(w2, m1w[h * 32 + 16 + c], sB);
        sC = fmaf(w2, m1b[h * 16 + c], sC);
    }
    const float Ac = sA * (0.0625f * LOG2E);
    const float Bc = sB * (0.5f * LOG2E);
    const float Cc = fmaf(0.5f, sC, m2b[h]) * LOG2E;

    // Q fragments (B-operand), split bf16
    Frag qh[2], ql[2];
    {
        const float* qrow = qg + base + (size_t)(t0g + gw * 16 + col) * 64;
#pragma unroll
        for (int ks = 0; ks < 2; ++ks) {
            const float4 f0 = *(const float4*)(qrow + ks * 32 + quad * 8);
            const float4 f1 = *(const float4*)(qrow + ks * 32 + quad * 8 + 4);
            packsplit(f0.x, f0.y, qh[ks].u[0], ql[ks].u[0]);
            packsplit(f0.z, f0.w, qh[ks].u[1], ql[ks].u[1]);
            packsplit(f1.x, f1.y, qh[ks].u[2], ql[ks].u[2]);
            packsplit(f1.z, f1.w, qh[ks].u[3], ql[ks].u[3]);
        }
    }

    float lsum = 0.f;                  // lane-local unnormalized softmax sum
    floatx4 oacc[4];
#pragma unroll
    for (int dt = 0; dt < 4; ++dt) oacc[dt] = floatx4{0.f, 0.f, 0.f, 0.f};

#pragma unroll 1
    for (int mc = 0; mc < 4; ++mc) {
        // JIT V/D loads (L2-resident after XCD remap; QK-phase covers them)
        float4 vp[4], dp[4];
#pragma unroll
        for (int i = 0; i < 4; ++i)
            vp[i] = *(const float4*)(vc + (size_t)(mc * 64 + 4 * m4 + i) * 64 + dgrp * 4);
#pragma unroll
        for (int mt = 0; mt < 4; ++mt)
            dp[mt] = *(const float4*)(Dc + mc * 64 + mt * 16);

        // pack K[mc] -> LDS (own 16 rows; XOR swizzle). kp was issued in the
        // previous iteration's PV phase (or the prologue) -> latency covered.
#pragma unroll
        for (int i = 0; i < 4; ++i) {
            uint32_t h0, l0, h1, l1;
            packsplit(kp[i].x, kp[i].y, h0, l0);
            packsplit(kp[i].z, kp[i].w, h1, l1);
            const int off = (8 * i + 2 * kqt) ^ ksw;
            *(uint2*)(KH + krow * 32 + off) = make_uint2(h0, h1);
            *(uint2*)(KL + krow * 32 + off) = make_uint2(l0, l1);
        }
        bar_lds();                             // --- bar1: K staged ---

        // S^T = K·Q^T via split bf16
        floatx4 sc[4];
        __builtin_amdgcn_s_setprio(1);
#pragma unroll
        for (int mt = 0; mt < 4; ++mt) {
            floatx4 acc = {0.f, 0.f, 0.f, 0.f};
#pragma unroll
            for (int ks = 0; ks < 2; ++ks) {
                const int ro = (mt * 16 + col) * 32 + ((16 * ks + 4 * quad) ^ rsw);
                Frag ah, al;
                ah.s = *(const short8*)(KH + ro);
                al.s = *(const short8*)(KL + ro);
                acc = MFMA(ah.s, qh[ks].s, acc);
                acc = MFMA(ah.s, ql[ks].s, acc);
                acc = MFMA(al.s, qh[ks].s, acc);
            }
            sc[mt] = acc;
        }
        __builtin_amdgcn_s_setprio(0);

        // pack V[mc] -> LDS (published by bar2); frees vp before MLP peak
#pragma unroll
        for (int jj = 0; jj < 4; ++jj) {
            uint32_t h0, l0, h1, l1;
            packsplit(((const float*)&vp[0])[jj], ((const float*)&vp[1])[jj], h0, l0);
            packsplit(((const float*)&vp[2])[jj], ((const float*)&vp[3])[jj], h1, l1);
            const int d = 4 * dgrp + jj;
            *(uint2*)(VH + d * 36 + cpV) = make_uint2(h0, h1);
            *(uint2*)(VL + d * 36 + cpV) = make_uint2(l0, l1);
        }

        // fused MLP in TWO HALVES of 8 elements (register-peak control).
        // mix = Cc + Bc*D + Ac*dot + sum_c (w2/2)|h_c|; |..| is free modifier.
        // P = 2^score written in-place into sc.
#pragma unroll
        for (int half = 0; half < 2; ++half) {
            float dvf[8], mix[8];
#pragma unroll
            for (int q2 = 0; q2 < 2; ++q2) {
                const float4 dd = dp[2 * half + q2];
                dvf[q2 * 4 + 0] = dd.x; dvf[q2 * 4 + 1] = dd.y;
                dvf[q2 * 4 + 2] = dd.z; dvf[q2 * 4 + 3] = dd.w;
            }
#pragma unroll
            for (int e = 0; e < 8; ++e) mix[e] = fmaf(dvf[e], Bc, Cc);
#pragma unroll 4
            for (int c = 0; c < 16; ++c) {
                const float4 wv = wlds[c];
#pragma unroll
                for (int e = 0; e < 8; ++e) {
                    const float s = sc[2 * half + (e >> 2)][e & 3];
                    const float hh = fmaf(s, wv.x, fmaf(dvf[e], wv.y, wv.z));
                    mix[e] = fmaf(fabsf(hh), wv.w, mix[e]);
                }
            }
#pragma unroll
            for (int e = 0; e < 8; ++e) {
                const float s = sc[2 * half + (e >> 2)][e & 3];
                const float p = fexp2(fmaf(s, Ac, mix[e]));
                sc[2 * half + (e >> 2)][e & 3] = p;    // P in place
                lsum += p;
            }
        }

        bar_lds();                             // --- bar2: QK reads done; V visible ---

        // P -> LDS (own rows in K region; swizzled like K). sc DIES here.
        const int prow = (gw * 16 + col) * 32;
#pragma unroll
        for (int mt = 0; mt < 4; ++mt) {
            uint32_t h0, l0, h1, l1;
            packsplit(sc[mt][0], sc[mt][1], h0, l0);
            packsplit(sc[mt][2], sc[mt][3], h1, l1);
            const int off = (mt * 8 + 2 * quad) ^ rsw;
            *(uint2*)(KH + prow + off) = make_uint2(h0, h1);
            *(uint2*)(KL + prow + off) = make_uint2(l0, l1);
        }

        // prefetch K[mc+1] NOW: sc just died, kp reuses its register slots
        // (disjoint live ranges -> MLP peak unchanged). PV below covers the
        // L2 latency; consumed by next iteration's K-pack.
        if (mc < 3) {
#pragma unroll
            for (int i = 0; i < 4; ++i)
                kp[i] = *(const float4*)(kc + (size_t)((mc + 1) * 64 + krow) * 64 + 16 * i + 4 * kqt);
        }

        // O += P·V   (no trailing barrier: next K-pack touches only OWN rows)
        __builtin_amdgcn_s_setprio(1);
#pragma unroll
        for (int ks = 0; ks < 2; ++ks) {
            const int po = prow + ((16 * ks + 4 * quad) ^ rsw);
            Frag pah, pal;
            pah.s = *(const short8*)(KH + po);
            pal.s = *(const short8*)(KL + po);
#pragma unroll
            for (int dt = 0; dt < 4; ++dt) {
                const int cbd = ((16 * ks + 4 * quad) + 8 * ((2 * dt + rsel) & 3)) & 31;
                const int vo = (dt * 16 + col) * 36 + cbd;
                Frag bhv, blv;
                bhv.s = *(const short8*)(VH + vo);
                blv.s = *(const short8*)(VL + vo);
                oacc[dt] = MFMA(pah.s, bhv.s, oacc[dt]);
                oacc[dt] = MFMA(pah.s, blv.s, oacc[dt]);
                oacc[dt] = MFMA(pal.s, bhv.s, oacc[dt]);
            }
        }
        __builtin_amdgcn_s_setprio(0);
    }

    bar_lds();                                 // all PV reads done before epilogue writes

    // single end-of-loop l reduction (t = col)
    lsum += __shfl_xor(lsum, 16, 64);
    lsum += __shfl_xor(lsum, 32, 64);

    // ================= combine the two m-halves, store =================
    float* smf = (float*)sm;
    if (group == 1) {
        if (quad == 0) smf[12864 + gw * 16 + col] = lsum;
        const int t = gw * 16 + quad * 4;
#pragma unroll
        for (int dt = 0; dt < 4; ++dt)
#pragma unroll
            for (int r = 0; r < 4; ++r)
                smf[8704 + (t + r) * 65 + dt * 16 + col] = oacc[dt][r];
    }
    bar_lds();
    if (group == 0) {
        const float l1c = smf[12864 + gw * 16 + col];
        const float rdn = 1.f / (lsum + l1c);
        float rdT[4];
#pragma unroll
        for (int r = 0; r < 4; ++r)
            rdT[r] = __shfl(rdn, quad * 4 + r, 64);
        const int t = gw * 16 + quad * 4;
        const size_t obase = ((size_t)b * 512 + t0g + t) * 1024 + h * 64 + col;
#pragma unroll
        for (int dt = 0; dt < 4; ++dt)
#pragma unroll
            for (int r = 0; r < 4; ++r) {
                const float o1 = smf[8704 + (t + r) * 65 + dt * 16 + col];
                outg[obase + (size_t)r * 1024 + dt * 16] = (oacc[dt][r] + o1) * rdT[r];
            }
    }
}

extern "C" void kernel_launch(void* const* d_in, const int* in_sizes, int n_in,
                              void* d_out, int out_size, void* d_ws, size_t ws_size,
                              hipStream_t stream) {
    const float* q   = (const float*)d_in[0];
    const float* k   = (const float*)d_in[1];
    const float* v   = (const float*)d_in[2];
    const float* dtm = (const float*)d_in[3];
    const float* m1w = (const float*)d_in[4];
    const float* m1b = (const float*)d_in[5];
    const float* m2w = (const float*)d_in[6];
    const float* m2b = (const float*)d_in[7];
    float* out = (float*)d_out;

    dim3 grid(4 * 16 * 8);   // 512 workgroups: (b,h) x 8 T-tiles
    dim3 block(512);         // 8 waves: 2 m-groups x 4 t-tiles
    msmha_flash<<<grid, block, 0, stream>>>(q, k, v, dtm, m1w, m1b, m2w, m2b, out);
}